// Round 1
// baseline (2936.319 us; speedup 1.0000x reference)
//
#include <hip/hip_runtime.h>

#define NEG_SLOPE 0.2f

constexpr int IN_F = 256;   // input feature dim
constexpr int NT   = 8;     // edge types
constexpr int NH   = 16;    // heads
constexpr int ND   = 16;    // head dim

// ---------------------------------------------------------------------------
// Kernel A: pre-contract weights with attn sums.
//   alsum[t][j] = sum_k attn_l[t, j, k]
//   Wl[t, i, h] = sum_j W[t, i, h*ND + j] * alsum[t][j]    (same for r)
// One block per type t, 256 threads (one per i).
// ---------------------------------------------------------------------------
__global__ void precompute_w_kernel(const float* __restrict__ W,
                                    const float* __restrict__ attn_l,
                                    const float* __restrict__ attn_r,
                                    float* __restrict__ Wl,
                                    float* __restrict__ Wr) {
    int t = blockIdx.x;
    __shared__ float alsum[NH];
    __shared__ float arsum[NH];
    int tid = threadIdx.x;
    if (tid < NH) {
        float a = 0.f, b = 0.f;
        for (int k = 0; k < ND; ++k) {
            a += attn_l[(t * NH + tid) * ND + k];
            b += attn_r[(t * NH + tid) * ND + k];
        }
        alsum[tid] = a;
        arsum[tid] = b;
    }
    __syncthreads();
    int i = tid;  // 0..255
    const float* wrow = W + ((size_t)t * IN_F + i) * (NH * ND);
    for (int h = 0; h < NH; ++h) {
        float sl = 0.f, sr = 0.f;
        for (int j = 0; j < ND; ++j) {
            float w = wrow[h * ND + j];
            sl += w * alsum[j];
            sr += w * arsum[j];
        }
        Wl[((size_t)t * IN_F + i) * NH + h] = sl;
        Wr[((size_t)t * IN_F + i) * NH + h] = sr;
    }
}

// ---------------------------------------------------------------------------
// Kernel B: per-node projections.
//   el[n,h] = sum_i x[n,i] * Wl[etype[n], i, h]   (same for er)
// Thread = (n, h); 16 consecutive threads share a node (x loads broadcast,
// Wl loads coalesced across h).
// ---------------------------------------------------------------------------
__global__ void node_proj_kernel(const float* __restrict__ x,
                                 const int* __restrict__ etype,
                                 const float* __restrict__ Wl,
                                 const float* __restrict__ Wr,
                                 float* __restrict__ el,
                                 float* __restrict__ er,
                                 int N) {
    int gid = blockIdx.x * blockDim.x + threadIdx.x;
    int n = gid >> 4;
    int h = gid & 15;
    if (n >= N) return;
    int t = etype[n];
    const float* xp = x + (size_t)n * IN_F;
    const float* wl = Wl + ((size_t)t * IN_F) * NH + h;
    const float* wr = Wr + ((size_t)t * IN_F) * NH + h;
    float al = 0.f, ar = 0.f;
    #pragma unroll 8
    for (int i = 0; i < IN_F; ++i) {
        float xv = xp[i];
        al += xv * wl[(size_t)i * NH];
        ar += xv * wr[(size_t)i * NH];
    }
    el[(size_t)n * NH + h] = al;
    er[(size_t)n * NH + h] = ar;
}

// ---------------------------------------------------------------------------
// Kernel C1: per-edge exp + per-(dst,h) sum.
//   e = leakyrelu(el[src] + er[dst]); ex = exp(e)  (softmax is shift-
//   invariant, values are O(10), so no max pass needed)
//   out[e,h] = ex; atomicAdd(ssum[dst,h], ex)
// Thread = edge; 16 h handled with float4.
// ---------------------------------------------------------------------------
__global__ void edge_exp_kernel(const int* __restrict__ src,
                                const int* __restrict__ dst,
                                const float* __restrict__ el,
                                const float* __restrict__ er,
                                float* __restrict__ out,
                                float* __restrict__ ssum,
                                int E) {
    int e = blockIdx.x * blockDim.x + threadIdx.x;
    if (e >= E) return;
    int s = src[e];
    int d = dst[e];
    const float4* a4 = reinterpret_cast<const float4*>(el + (size_t)s * NH);
    const float4* b4 = reinterpret_cast<const float4*>(er + (size_t)d * NH);
    float4* o4 = reinterpret_cast<float4*>(out + (size_t)e * NH);
    float* sp = ssum + (size_t)d * NH;
    #pragma unroll
    for (int q = 0; q < 4; ++q) {
        float4 a = a4[q];
        float4 b = b4[q];
        float v0 = a.x + b.x, v1 = a.y + b.y, v2 = a.z + b.z, v3 = a.w + b.w;
        v0 = v0 > 0.f ? v0 : NEG_SLOPE * v0;
        v1 = v1 > 0.f ? v1 : NEG_SLOPE * v1;
        v2 = v2 > 0.f ? v2 : NEG_SLOPE * v2;
        v3 = v3 > 0.f ? v3 : NEG_SLOPE * v3;
        float e0 = __expf(v0), e1 = __expf(v1), e2 = __expf(v2), e3 = __expf(v3);
        float4 o; o.x = e0; o.y = e1; o.z = e2; o.w = e3;
        o4[q] = o;
        atomicAdd(sp + q * 4 + 0, e0);
        atomicAdd(sp + q * 4 + 1, e1);
        atomicAdd(sp + q * 4 + 2, e2);
        atomicAdd(sp + q * 4 + 3, e3);
    }
}

// ---------------------------------------------------------------------------
// Kernel C2: normalize.
// ---------------------------------------------------------------------------
__global__ void edge_norm_kernel(const int* __restrict__ dst,
                                 const float* __restrict__ ssum,
                                 float* __restrict__ out,
                                 int E) {
    int e = blockIdx.x * blockDim.x + threadIdx.x;
    if (e >= E) return;
    int d = dst[e];
    const float4* s4 = reinterpret_cast<const float4*>(ssum + (size_t)d * NH);
    float4* o4 = reinterpret_cast<float4*>(out + (size_t)e * NH);
    #pragma unroll
    for (int q = 0; q < 4; ++q) {
        float4 o = o4[q];
        float4 s = s4[q];
        o.x /= s.x; o.y /= s.y; o.z /= s.z; o.w /= s.w;
        o4[q] = o;
    }
}

extern "C" void kernel_launch(void* const* d_in, const int* in_sizes, int n_in,
                              void* d_out, int out_size, void* d_ws, size_t ws_size,
                              hipStream_t stream) {
    const float* x      = (const float*)d_in[0];  // [N, 256]
    const float* W      = (const float*)d_in[1];  // [8, 256, 256]
    const float* attn_l = (const float*)d_in[2];  // [8, 16, 16]
    const float* attn_r = (const float*)d_in[3];  // [8, 16, 16]
    const int*   etype  = (const int*)d_in[4];    // [N]
    const int*   src    = (const int*)d_in[5];    // [E]
    const int*   dst    = (const int*)d_in[6];    // [E]

    int N = in_sizes[4];
    int E = in_sizes[5];

    float* out = (float*)d_out;  // [E, 16]

    // Workspace layout (floats), all offsets 256B-aligned.
    char* ws = (char*)d_ws;
    float* Wl   = (float*)ws;                          // 8*256*16 = 32768 floats
    float* Wr   = Wl + (size_t)NT * IN_F * NH;
    float* el   = Wr + (size_t)NT * IN_F * NH;         // N*16
    float* er   = el + (size_t)N * NH;                 // N*16
    float* ssum = er + (size_t)N * NH;                 // N*16

    hipMemsetAsync(ssum, 0, (size_t)N * NH * sizeof(float), stream);

    precompute_w_kernel<<<NT, 256, 0, stream>>>(W, attn_l, attn_r, Wl, Wr);

    int nb_node = (N * NH + 255) / 256;
    node_proj_kernel<<<nb_node, 256, 0, stream>>>(x, etype, Wl, Wr, el, er, N);

    int nb_edge = (E + 255) / 256;
    edge_exp_kernel<<<nb_edge, 256, 0, stream>>>(src, dst, el, er, out, ssum, E);
    edge_norm_kernel<<<nb_edge, 256, 0, stream>>>(dst, ssum, out, E);
}

// Round 2
// 667.587 us; speedup vs baseline: 4.3984x; 4.3984x over previous
//
#include <hip/hip_runtime.h>

#define NEG_SLOPE 0.2f

constexpr int IN_F = 256;   // input feature dim
constexpr int NT   = 8;     // edge types
constexpr int NH   = 16;    // heads
constexpr int ND   = 16;    // head dim

// ---------------------------------------------------------------------------
// Kernel A: pre-contract weights with attn sums.
//   alsum[t][j] = sum_k attn_l[t, j, k]
//   Wl[t, i, h] = sum_j W[t, i, h*ND + j] * alsum[t][j]    (same for r)
// ---------------------------------------------------------------------------
__global__ void precompute_w_kernel(const float* __restrict__ W,
                                    const float* __restrict__ attn_l,
                                    const float* __restrict__ attn_r,
                                    float* __restrict__ Wl,
                                    float* __restrict__ Wr) {
    int t = blockIdx.x;
    __shared__ float alsum[NH];
    __shared__ float arsum[NH];
    int tid = threadIdx.x;
    if (tid < NH) {
        float a = 0.f, b = 0.f;
        for (int k = 0; k < ND; ++k) {
            a += attn_l[(t * NH + tid) * ND + k];
            b += attn_r[(t * NH + tid) * ND + k];
        }
        alsum[tid] = a;
        arsum[tid] = b;
    }
    __syncthreads();
    int i = tid;  // 0..255
    const float* wrow = W + ((size_t)t * IN_F + i) * (NH * ND);
    for (int h = 0; h < NH; ++h) {
        float sl = 0.f, sr = 0.f;
        for (int j = 0; j < ND; ++j) {
            float w = wrow[h * ND + j];
            sl += w * alsum[j];
            sr += w * arsum[j];
        }
        Wl[((size_t)t * IN_F + i) * NH + h] = sl;
        Wr[((size_t)t * IN_F + i) * NH + h] = sr;
    }
}

// ---------------------------------------------------------------------------
// Kernel B: per-node projections.
//   el[n,h] = sum_i x[n,i] * Wl[etype[n], i, h]   (same for er)
// ---------------------------------------------------------------------------
__global__ void node_proj_kernel(const float* __restrict__ x,
                                 const int* __restrict__ etype,
                                 const float* __restrict__ Wl,
                                 const float* __restrict__ Wr,
                                 float* __restrict__ el,
                                 float* __restrict__ er,
                                 int N) {
    int gid = blockIdx.x * blockDim.x + threadIdx.x;
    int n = gid >> 4;
    int h = gid & 15;
    if (n >= N) return;
    int t = etype[n];
    const float* xp = x + (size_t)n * IN_F;
    const float* wl = Wl + ((size_t)t * IN_F) * NH + h;
    const float* wr = Wr + ((size_t)t * IN_F) * NH + h;
    float al = 0.f, ar = 0.f;
    #pragma unroll 8
    for (int i = 0; i < IN_F; ++i) {
        float xv = xp[i];
        al += xv * wl[(size_t)i * NH];
        ar += xv * wr[(size_t)i * NH];
    }
    el[(size_t)n * NH + h] = al;
    er[(size_t)n * NH + h] = ar;
}

// ---------------------------------------------------------------------------
// Kernel C: counting-sort pass 1 — in-degree count + stable position.
//   pos[e] = old value of cnt[dst[e]]++   (one int atomic per edge)
// ---------------------------------------------------------------------------
__global__ void count_pos_kernel(const int* __restrict__ dst,
                                 int* __restrict__ cnt,
                                 int* __restrict__ pos,
                                 int E) {
    int e = blockIdx.x * blockDim.x + threadIdx.x;
    if (e >= E) return;
    pos[e] = atomicAdd(&cnt[dst[e]], 1);
}

// ---------------------------------------------------------------------------
// Kernel D: exclusive scan of cnt -> start. Single 1024-thread block,
// grid-stride with running carry. N=100k -> 98 iterations, ~40us.
// ---------------------------------------------------------------------------
__global__ void scan_kernel(const int* __restrict__ cnt,
                            int* __restrict__ start,
                            int N) {
    __shared__ int wsum[16];
    int tid = threadIdx.x;
    int lane = tid & 63;
    int w = tid >> 6;
    int carry = 0;
    for (int base = 0; base < N; base += 1024) {
        int i = base + tid;
        int c = (i < N) ? cnt[i] : 0;
        // wave-inclusive scan
        int v = c;
        #pragma unroll
        for (int off = 1; off < 64; off <<= 1) {
            int u = __shfl_up(v, (unsigned)off);
            v += (lane >= off) ? u : 0;
        }
        if (lane == 63) wsum[w] = v;
        __syncthreads();
        if (w == 0 && lane < 16) {
            int t = wsum[lane];
            #pragma unroll
            for (int off = 1; off < 16; off <<= 1) {
                int u = __shfl_up(t, (unsigned)off);
                t += (lane >= off) ? u : 0;
            }
            wsum[lane] = t;  // inclusive scan of wave totals
        }
        __syncthreads();
        int woff = (w == 0) ? 0 : wsum[w - 1];
        if (i < N) start[i] = carry + woff + v - c;  // exclusive
        int total = wsum[15];
        __syncthreads();  // protect wsum before next iteration
        carry += total;
    }
}

// ---------------------------------------------------------------------------
// Kernel E: counting-sort pass 2 — scatter (edge id, src[e]) into dst-grouped
// order so the softmax pass reads its segment coalesced.
// ---------------------------------------------------------------------------
__global__ void scatter_kernel(const int* __restrict__ dst,
                               const int* __restrict__ src,
                               const int* __restrict__ pos,
                               const int* __restrict__ start,
                               int2* __restrict__ esrc,
                               int E) {
    int e = blockIdx.x * blockDim.x + threadIdx.x;
    if (e >= E) return;
    int d = dst[e];
    int p = start[d] + pos[e];
    esrc[p] = make_int2(e, src[e]);
}

// ---------------------------------------------------------------------------
// Kernel F: wave-per-node fused exp + sum + normalize.
//   lane = k*16 + h ; 4 lane-groups stride the node's edge segment.
//   Pass 1: s[h] = sum_e exp(lrelu(el[src,h] + er[d,h])) (in-register,
//           shfl_xor reduce over k). Pass 2: recompute (L1/L2-hot) and write
//           a = exp/s directly. out written once, never re-read.
// ---------------------------------------------------------------------------
__global__ void node_softmax_kernel(const int2* __restrict__ esrc,
                                    const int* __restrict__ start,
                                    const int* __restrict__ cnt,
                                    const float* __restrict__ el,
                                    const float* __restrict__ er,
                                    float* __restrict__ out,
                                    int N) {
    int gw = (int)((blockIdx.x * (size_t)blockDim.x + threadIdx.x) >> 6);
    if (gw >= N) return;
    int lane = threadIdx.x & 63;
    int h = lane & 15;
    int k = lane >> 4;
    int off = start[gw];
    int m = cnt[gw];
    if (m == 0) return;
    float erh = er[(size_t)gw * NH + h];

    float s = 0.f;
    for (int j = k; j < m; j += 4) {
        int2 es = esrc[off + j];
        float v = el[(size_t)es.y * NH + h] + erh;
        v = v > 0.f ? v : NEG_SLOPE * v;
        s += __expf(v);
    }
    s += __shfl_xor(s, 16);
    s += __shfl_xor(s, 32);
    float inv = 1.0f / s;

    for (int j = k; j < m; j += 4) {
        int2 es = esrc[off + j];
        float v = el[(size_t)es.y * NH + h] + erh;
        v = v > 0.f ? v : NEG_SLOPE * v;
        out[(size_t)es.x * NH + h] = __expf(v) * inv;
    }
}

extern "C" void kernel_launch(void* const* d_in, const int* in_sizes, int n_in,
                              void* d_out, int out_size, void* d_ws, size_t ws_size,
                              hipStream_t stream) {
    const float* x      = (const float*)d_in[0];  // [N, 256]
    const float* W      = (const float*)d_in[1];  // [8, 256, 256]
    const float* attn_l = (const float*)d_in[2];  // [8, 16, 16]
    const float* attn_r = (const float*)d_in[3];  // [8, 16, 16]
    const int*   etype  = (const int*)d_in[4];    // [N]
    const int*   src    = (const int*)d_in[5];    // [E]
    const int*   dst    = (const int*)d_in[6];    // [E]

    int N = in_sizes[4];
    int E = in_sizes[5];

    float* out = (float*)d_out;  // [E, 16]

    // Workspace layout (all chunks naturally aligned; ~52.3 MB total).
    char* ws = (char*)d_ws;
    float* Wl    = (float*)ws;                                  // 8*256*16
    float* Wr    = Wl + (size_t)NT * IN_F * NH;                 // 8*256*16
    float* el    = Wr + (size_t)NT * IN_F * NH;                 // N*16
    float* er    = el + (size_t)N * NH;                         // N*16
    int*   cnt   = (int*)(er + (size_t)N * NH);                 // N
    int*   startv= cnt + N;                                     // N
    int*   pos   = startv + N;                                  // E
    int2*  esrc  = (int2*)(pos + E);                            // E int2 (8B-aligned: preceding ints are even counts)

    hipMemsetAsync(cnt, 0, (size_t)N * sizeof(int), stream);

    precompute_w_kernel<<<NT, 256, 0, stream>>>(W, attn_l, attn_r, Wl, Wr);

    int nb_node = (N * NH + 255) / 256;
    node_proj_kernel<<<nb_node, 256, 0, stream>>>(x, etype, Wl, Wr, el, er, N);

    int nb_edge = (E + 255) / 256;
    count_pos_kernel<<<nb_edge, 256, 0, stream>>>(dst, cnt, pos, E);
    scan_kernel<<<1, 1024, 0, stream>>>(cnt, startv, N);
    scatter_kernel<<<nb_edge, 256, 0, stream>>>(dst, src, pos, startv, esrc, E);

    int nb_sm = (int)(((size_t)N * 64 + 255) / 256);
    node_softmax_kernel<<<nb_sm, 256, 0, stream>>>(esrc, startv, cnt, el, er, out, N);
}

// Round 3
// 587.126 us; speedup vs baseline: 5.0012x; 1.1370x over previous
//
#include <hip/hip_runtime.h>

#define NEG_SLOPE 0.2f

constexpr int IN_F = 256;   // input feature dim
constexpr int NT   = 8;     // edge types
constexpr int NH   = 16;    // heads
constexpr int ND   = 16;    // head dim
constexpr int CAP  = 96;    // LDS-buffered edges per node in softmax

// ---------------------------------------------------------------------------
// Kernel A: pre-contract weights with attn sums, packed for the proj kernel.
//   alsum[t][j] = sum_k attn_l[t, j, k]
//   sl[h] = sum_j W[t, i, h*ND + j] * alsum[t][j]   (sr with arsum)
//   Wc[(t*256+i)*8 + q] = float4(sl[q], sl[q+8], sr[q], sr[q+8])
// ---------------------------------------------------------------------------
__global__ void precompute_w_kernel(const float* __restrict__ W,
                                    const float* __restrict__ attn_l,
                                    const float* __restrict__ attn_r,
                                    float4* __restrict__ Wc) {
    int t = blockIdx.x;
    __shared__ float alsum[NH];
    __shared__ float arsum[NH];
    int tid = threadIdx.x;
    if (tid < NH) {
        float a = 0.f, b = 0.f;
        for (int k = 0; k < ND; ++k) {
            a += attn_l[(t * NH + tid) * ND + k];
            b += attn_r[(t * NH + tid) * ND + k];
        }
        alsum[tid] = a;
        arsum[tid] = b;
    }
    __syncthreads();
    int i = tid;  // 0..255
    const float* wrow = W + ((size_t)t * IN_F + i) * (NH * ND);
    float sl[NH], sr[NH];
    for (int h = 0; h < NH; ++h) {
        float a = 0.f, b = 0.f;
        for (int j = 0; j < ND; ++j) {
            float w = wrow[h * ND + j];
            a += w * alsum[j];
            b += w * arsum[j];
        }
        sl[h] = a;
        sr[h] = b;
    }
    float4* dst = Wc + ((size_t)t * IN_F + i) * 8;
    for (int q = 0; q < 8; ++q) {
        float4 v;
        v.x = sl[q]; v.y = sl[q + 8]; v.z = sr[q]; v.w = sr[q + 8];
        dst[q] = v;
    }
}

// ---------------------------------------------------------------------------
// Kernel B v2: per-node projections, LDS-staged x.
//   Block = 256 threads = 32 nodes; x tile loaded coalesced (float4),
//   compute thread (node, q) accumulates h=q and h=q+8 for both l and r
//   from one packed float4 weight load per i.
// ---------------------------------------------------------------------------
constexpr int TM = 32;
__global__ __launch_bounds__(256) void node_proj_kernel(
        const float* __restrict__ x,
        const int* __restrict__ etype,
        const float4* __restrict__ Wc,
        float* __restrict__ el,
        float* __restrict__ er,
        int N) {
    __shared__ float xs[TM][IN_F + 4];  // stride 260 -> conflict-free
    int tid = threadIdx.x;
    int n0 = blockIdx.x * TM;
    int nrows = min(TM, N - n0);

    #pragma unroll
    for (int j = 0; j < 8; ++j) {
        int flat = j * 1024 + tid * 4;  // float index in 32x256 tile
        int r = flat >> 8, c = flat & 255;
        if (r < nrows) {
            *(float4*)&xs[r][c] = *(const float4*)&x[(size_t)(n0 + r) * IN_F + c];
        }
    }
    __syncthreads();

    int nl = tid >> 3, q = tid & 7;
    int n = n0 + nl;
    if (n >= N) return;
    int t = etype[n];
    const float4* wc = Wc + (size_t)t * IN_F * 8 + q;
    float al0 = 0.f, al1 = 0.f, ar0 = 0.f, ar1 = 0.f;
    #pragma unroll 4
    for (int i = 0; i < IN_F; ++i) {
        float xv = xs[nl][i];
        float4 w = wc[(size_t)i * 8];
        al0 += xv * w.x; al1 += xv * w.y;
        ar0 += xv * w.z; ar1 += xv * w.w;
    }
    el[(size_t)n * NH + q]     = al0;
    el[(size_t)n * NH + q + 8] = al1;
    er[(size_t)n * NH + q]     = ar0;
    er[(size_t)n * NH + q + 8] = ar1;
}

// ---------------------------------------------------------------------------
// Kernel C: counting-sort pass 1 — in-degree count + stable position.
// ---------------------------------------------------------------------------
__global__ void count_pos_kernel(const int* __restrict__ dst,
                                 int* __restrict__ cnt,
                                 int* __restrict__ pos,
                                 int E) {
    int e = blockIdx.x * blockDim.x + threadIdx.x;
    if (e >= E) return;
    pos[e] = atomicAdd(&cnt[dst[e]], 1);
}

// ---------------------------------------------------------------------------
// Kernel D v2: exclusive scan of cnt -> start. Single 1024-thread block,
// int4 per thread (4096/iter), running carry.
// ---------------------------------------------------------------------------
__global__ void scan_kernel(const int* __restrict__ cnt,
                            int* __restrict__ start,
                            int N) {
    __shared__ int wsum[16];
    int tid = threadIdx.x;
    int lane = tid & 63;
    int w = tid >> 6;
    int carry = 0;
    for (int base = 0; base < N; base += 4096) {
        int i = base + tid * 4;
        int4 c = make_int4(0, 0, 0, 0);
        if (i + 3 < N) {
            c = *(const int4*)&cnt[i];
        } else {
            if (i     < N) c.x = cnt[i];
            if (i + 1 < N) c.y = cnt[i + 1];
            if (i + 2 < N) c.z = cnt[i + 2];
            if (i + 3 < N) c.w = cnt[i + 3];
        }
        int tsum = c.x + c.y + c.z + c.w;
        int v = tsum;
        #pragma unroll
        for (int off = 1; off < 64; off <<= 1) {
            int u = __shfl_up(v, (unsigned)off);
            v += (lane >= off) ? u : 0;
        }
        if (lane == 63) wsum[w] = v;
        __syncthreads();
        if (w == 0 && lane < 16) {
            int t = wsum[lane];
            #pragma unroll
            for (int off = 1; off < 16; off <<= 1) {
                int u = __shfl_up(t, (unsigned)off);
                t += (lane >= off) ? u : 0;
            }
            wsum[lane] = t;
        }
        __syncthreads();
        int woff = (w == 0) ? 0 : wsum[w - 1];
        int ex = carry + woff + v - tsum;  // exclusive prefix for c.x
        if (i < N) {
            start[i] = ex;
            if (i + 1 < N) start[i + 1] = ex + c.x;
            if (i + 2 < N) start[i + 2] = ex + c.x + c.y;
            if (i + 3 < N) start[i + 3] = ex + c.x + c.y + c.z;
        }
        int total = wsum[15];
        __syncthreads();
        carry += total;
    }
}

// ---------------------------------------------------------------------------
// Kernel E: counting-sort pass 2 — scatter (edge id, src[e]).
// ---------------------------------------------------------------------------
__global__ void scatter_kernel(const int* __restrict__ dst,
                               const int* __restrict__ src,
                               const int* __restrict__ pos,
                               const int* __restrict__ start,
                               int2* __restrict__ esrc,
                               int E) {
    int e = blockIdx.x * blockDim.x + threadIdx.x;
    if (e >= E) return;
    int d = dst[e];
    int p = start[d] + pos[e];
    esrc[p] = make_int2(e, src[e]);
}

// ---------------------------------------------------------------------------
// Kernel F v2: wave-per-node fused exp + sum + normalize, LDS exp buffer.
//   lane = k*16 + h; 4 lane-groups stride the node's edges. Pass 1 computes
//   exp, stashes the first CAP edges' values in LDS, accumulates s.
//   Pass 2 reads LDS (or recomputes for the rare deg>CAP tail) and writes
//   out = exp/s. out written once, never re-read; el gathered once.
// ---------------------------------------------------------------------------
__global__ __launch_bounds__(256) void node_softmax_kernel(
        const int2* __restrict__ esrc,
        const int* __restrict__ start,
        const int* __restrict__ cnt,
        const float* __restrict__ el,
        const float* __restrict__ er,
        float* __restrict__ out,
        int N) {
    __shared__ float exs[4][CAP * NH];  // 24 KB
    int wl = threadIdx.x >> 6;
    int gw = blockIdx.x * 4 + wl;
    if (gw >= N) return;
    int lane = threadIdx.x & 63;
    int h = lane & 15;
    int k = lane >> 4;
    int off = start[gw];
    int m = cnt[gw];
    if (m == 0) return;
    float erh = er[(size_t)gw * NH + h];
    float* exw = exs[wl];

    float s = 0.f;
    for (int j = k; j < m; j += 4) {
        int2 es = esrc[off + j];
        float v = el[(size_t)es.y * NH + h] + erh;
        v = v > 0.f ? v : NEG_SLOPE * v;
        float ex = __expf(v);
        if (j < CAP) exw[j * NH + h] = ex;
        s += ex;
    }
    s += __shfl_xor(s, 16);
    s += __shfl_xor(s, 32);
    float inv = 1.0f / s;

    for (int j = k; j < m; j += 4) {
        int2 es = esrc[off + j];
        float ex;
        if (j < CAP) {
            ex = exw[j * NH + h];
        } else {
            float v = el[(size_t)es.y * NH + h] + erh;
            v = v > 0.f ? v : NEG_SLOPE * v;
            ex = __expf(v);
        }
        out[(size_t)es.x * NH + h] = ex * inv;
    }
}

extern "C" void kernel_launch(void* const* d_in, const int* in_sizes, int n_in,
                              void* d_out, int out_size, void* d_ws, size_t ws_size,
                              hipStream_t stream) {
    const float* x      = (const float*)d_in[0];  // [N, 256]
    const float* W      = (const float*)d_in[1];  // [8, 256, 256]
    const float* attn_l = (const float*)d_in[2];  // [8, 16, 16]
    const float* attn_r = (const float*)d_in[3];  // [8, 16, 16]
    const int*   etype  = (const int*)d_in[4];    // [N]
    const int*   src    = (const int*)d_in[5];    // [E]
    const int*   dst    = (const int*)d_in[6];    // [E]

    int N = in_sizes[4];
    int E = in_sizes[5];

    float* out = (float*)d_out;  // [E, 16]

    // Workspace layout (floats/ints), 16B alignment maintained throughout.
    char* ws = (char*)d_ws;
    float4* Wc   = (float4*)ws;                       // 8*256*8 float4 = 256 KB
    float*  el   = (float*)(Wc + (size_t)NT * IN_F * 8);  // N*16
    float*  er   = el + (size_t)N * NH;               // N*16
    int*    cnt  = (int*)(er + (size_t)N * NH);       // N
    int*    startv = cnt + N;                         // N
    int*    pos  = startv + N;                        // E
    int2*   esrc = (int2*)(pos + E);                  // E int2

    hipMemsetAsync(cnt, 0, (size_t)N * sizeof(int), stream);

    precompute_w_kernel<<<NT, 256, 0, stream>>>(W, attn_l, attn_r, Wc);

    int nb_proj = (N + TM - 1) / TM;
    node_proj_kernel<<<nb_proj, 256, 0, stream>>>(x, etype, Wc, el, er, N);

    int nb_edge = (E + 255) / 256;
    count_pos_kernel<<<nb_edge, 256, 0, stream>>>(dst, cnt, pos, E);
    scan_kernel<<<1, 1024, 0, stream>>>(cnt, startv, N);
    scatter_kernel<<<nb_edge, 256, 0, stream>>>(dst, src, pos, startv, esrc, E);

    int nb_sm = (N + 3) / 4;
    node_softmax_kernel<<<nb_sm, 256, 0, stream>>>(esrc, startv, cnt, el, er, out, N);
}

// Round 5
// 574.725 us; speedup vs baseline: 5.1091x; 1.0216x over previous
//
#include <hip/hip_runtime.h>

#define NEG_SLOPE 0.2f

constexpr int IN_F = 256;   // input feature dim
constexpr int NT   = 8;     // edge types
constexpr int NH   = 16;    // heads
constexpr int ND   = 16;    // head dim

// ---------------------------------------------------------------------------
// Kernel A: pre-contract weights with attn sums, packed for the proj kernel.
//   alsum[t][j] = sum_k attn_l[t, j, k]
//   sl[h] = sum_j W[t, i, h*ND + j] * alsum[t][j]   (sr with arsum)
//   Wc[(t*256+i)*8 + q] = float4(sl[q], sl[q+8], sr[q], sr[q+8])
// ---------------------------------------------------------------------------
__global__ void precompute_w_kernel(const float* __restrict__ W,
                                    const float* __restrict__ attn_l,
                                    const float* __restrict__ attn_r,
                                    float4* __restrict__ Wc) {
    int t = blockIdx.x;
    __shared__ float alsum[NH];
    __shared__ float arsum[NH];
    int tid = threadIdx.x;
    if (tid < NH) {
        float a = 0.f, b = 0.f;
        for (int k = 0; k < ND; ++k) {
            a += attn_l[(t * NH + tid) * ND + k];
            b += attn_r[(t * NH + tid) * ND + k];
        }
        alsum[tid] = a;
        arsum[tid] = b;
    }
    __syncthreads();
    int i = tid;  // 0..255
    const float* wrow = W + ((size_t)t * IN_F + i) * (NH * ND);
    float sl[NH], sr[NH];
    for (int h = 0; h < NH; ++h) {
        float a = 0.f, b = 0.f;
        for (int j = 0; j < ND; ++j) {
            float w = wrow[h * ND + j];
            a += w * alsum[j];
            b += w * arsum[j];
        }
        sl[h] = a;
        sr[h] = b;
    }
    float4* dst = Wc + ((size_t)t * IN_F + i) * 8;
    for (int q = 0; q < 8; ++q) {
        float4 v;
        v.x = sl[q]; v.y = sl[q + 8]; v.z = sr[q]; v.w = sr[q + 8];
        dst[q] = v;
    }
}

// ---------------------------------------------------------------------------
// Kernel B: per-node projections, LDS-staged x.
//   el[n,h] -> own array; er[n,h] -> ernv[n*16+h].x (packed with 1/s).
// ---------------------------------------------------------------------------
constexpr int TM = 32;
__global__ __launch_bounds__(256) void node_proj_kernel(
        const float* __restrict__ x,
        const int* __restrict__ etype,
        const float4* __restrict__ Wc,
        float* __restrict__ el,
        float* __restrict__ ernv,   // float2 viewed flat: [N*16*2]
        int N) {
    __shared__ float xs[TM][IN_F + 4];  // stride 260 -> conflict-free
    int tid = threadIdx.x;
    int n0 = blockIdx.x * TM;
    int nrows = min(TM, N - n0);

    #pragma unroll
    for (int j = 0; j < 8; ++j) {
        int flat = j * 1024 + tid * 4;  // float index in 32x256 tile
        int r = flat >> 8, c = flat & 255;
        if (r < nrows) {
            *(float4*)&xs[r][c] = *(const float4*)&x[(size_t)(n0 + r) * IN_F + c];
        }
    }
    __syncthreads();

    int nl = tid >> 3, q = tid & 7;
    int n = n0 + nl;
    if (n >= N) return;
    int t = etype[n];
    const float4* wc = Wc + (size_t)t * IN_F * 8 + q;
    float al0 = 0.f, al1 = 0.f, ar0 = 0.f, ar1 = 0.f;
    #pragma unroll 4
    for (int i = 0; i < IN_F; ++i) {
        float xv = xs[nl][i];
        float4 w = wc[(size_t)i * 8];
        al0 += xv * w.x; al1 += xv * w.y;
        ar0 += xv * w.z; ar1 += xv * w.w;
    }
    el[(size_t)n * NH + q]     = al0;
    el[(size_t)n * NH + q + 8] = al1;
    ernv[((size_t)n * NH + q) * 2]       = ar0;
    ernv[((size_t)n * NH + q + 8) * 2]   = ar1;
}

// ---------------------------------------------------------------------------
// Kernel C: counting-sort pass 1 — in-degree count + position.
// ---------------------------------------------------------------------------
__global__ void count_pos_kernel(const int* __restrict__ dst,
                                 int* __restrict__ cnt,
                                 int* __restrict__ pos,
                                 int E) {
    int e = blockIdx.x * blockDim.x + threadIdx.x;
    if (e >= E) return;
    pos[e] = atomicAdd(&cnt[dst[e]], 1);
}

// ---------------------------------------------------------------------------
// Kernel D: exclusive scan of cnt -> start. Single 1024-thread block,
// int4 per thread (4096/iter), running carry.
// ---------------------------------------------------------------------------
__global__ void scan_kernel(const int* __restrict__ cnt,
                            int* __restrict__ start,
                            int N) {
    __shared__ int wsum[16];
    int tid = threadIdx.x;
    int lane = tid & 63;
    int w = tid >> 6;
    int carry = 0;
    for (int base = 0; base < N; base += 4096) {
        int i = base + tid * 4;
        int4 c = make_int4(0, 0, 0, 0);
        if (i + 3 < N) {
            c = *(const int4*)&cnt[i];
        } else {
            if (i     < N) c.x = cnt[i];
            if (i + 1 < N) c.y = cnt[i + 1];
            if (i + 2 < N) c.z = cnt[i + 2];
            if (i + 3 < N) c.w = cnt[i + 3];
        }
        int tsum = c.x + c.y + c.z + c.w;
        int v = tsum;
        #pragma unroll
        for (int off = 1; off < 64; off <<= 1) {
            int u = __shfl_up(v, (unsigned)off);
            v += (lane >= off) ? u : 0;
        }
        if (lane == 63) wsum[w] = v;
        __syncthreads();
        if (w == 0 && lane < 16) {
            int t = wsum[lane];
            #pragma unroll
            for (int off = 1; off < 16; off <<= 1) {
                int u = __shfl_up(t, (unsigned)off);
                t += (lane >= off) ? u : 0;
            }
            wsum[lane] = t;
        }
        __syncthreads();
        int woff = (w == 0) ? 0 : wsum[w - 1];
        int ex = carry + woff + v - tsum;  // exclusive prefix for c.x
        if (i < N) {
            start[i] = ex;
            if (i + 1 < N) start[i + 1] = ex + c.x;
            if (i + 2 < N) start[i + 2] = ex + c.x + c.y;
            if (i + 3 < N) start[i + 3] = ex + c.x + c.y + c.z;
        }
        int total = wsum[15];
        __syncthreads();
        carry += total;
    }
}

// ---------------------------------------------------------------------------
// Kernel E: counting-sort pass 2 — scatter src only (4B payload).
// ---------------------------------------------------------------------------
__global__ void scatter_kernel(const int* __restrict__ dst,
                               const int* __restrict__ src,
                               const int* __restrict__ pos,
                               const int* __restrict__ start,
                               int* __restrict__ srcs,
                               int E) {
    int e = blockIdx.x * blockDim.x + threadIdx.x;
    if (e >= E) return;
    int d = dst[e];
    srcs[start[d] + pos[e]] = src[e];
}

// ---------------------------------------------------------------------------
// Kernel F: wave-per-node softmax denominator.
//   All 64 lanes load a 64-edge chunk of sorted srcs in ONE coalesced
//   request, then shfl-broadcast into the 4 lane-groups (k = lane>>4).
//   The broadcast loop trip count is WAVE-UNIFORM (steps = ceil(lim/4));
//   __shfl source lane is clamped so every ds_bpermute executes with all
//   64 lanes active (reading an exec-masked-off lane is undefined — that
//   was round 4's bug). s[h] reduced in-register; 1/s -> ernv[.].y.
// ---------------------------------------------------------------------------
__global__ __launch_bounds__(256) void node_sum_kernel(
        const int* __restrict__ srcs,
        const int* __restrict__ start,
        const int* __restrict__ cnt,
        const float* __restrict__ el,
        float* __restrict__ ernv,   // float2 flat
        int N) {
    int gw = blockIdx.x * 4 + (threadIdx.x >> 6);
    if (gw >= N) return;
    int lane = threadIdx.x & 63;
    int h = lane & 15;
    int k = lane >> 4;
    int off = start[gw];
    int m = cnt[gw];
    if (m == 0) return;
    float erh = ernv[((size_t)gw * NH + h) * 2];

    float s = 0.f;
    for (int base = 0; base < m; base += 64) {
        int idx = base + lane;
        int sid = (idx < m) ? srcs[off + idx] : 0;
        int lim = min(64, m - base);
        int steps = (lim + 3) >> 2;  // uniform across all 4 lane-groups
        for (int i = 0; i < steps; ++i) {
            int j = k + 4 * i;
            int srcLane = j < lim ? j : 0;       // clamp: all lanes active
            int sj = __shfl(sid, srcLane);
            if (j < lim) {
                float v = el[(size_t)sj * NH + h] + erh;
                v = v > 0.f ? v : NEG_SLOPE * v;
                s += __expf(v);
            }
        }
    }
    s += __shfl_xor(s, 16);
    s += __shfl_xor(s, 32);
    if (k == 0) {
        ernv[((size_t)gw * NH + h) * 2 + 1] = 1.0f / s;
    }
}

// ---------------------------------------------------------------------------
// Kernel G: final edge pass in ORIGINAL edge order — fully coalesced out.
//   thread = (e, h); gathers el[src] (64B/edge) + ernv[dst] (128B/edge).
// ---------------------------------------------------------------------------
__global__ __launch_bounds__(256) void final_edge_kernel(
        const int* __restrict__ src,
        const int* __restrict__ dst,
        const float* __restrict__ el,
        const float2* __restrict__ ernv,
        float* __restrict__ out,
        int E) {
    size_t gid = (size_t)blockIdx.x * blockDim.x + threadIdx.x;
    int e = (int)(gid >> 4);
    int h = (int)(gid & 15);
    if (e >= E) return;
    int s = src[e];
    int d = dst[e];
    float elv = el[(size_t)s * NH + h];
    float2 rn = ernv[(size_t)d * NH + h];
    float v = elv + rn.x;
    v = v > 0.f ? v : NEG_SLOPE * v;
    out[(size_t)e * NH + h] = __expf(v) * rn.y;
}

extern "C" void kernel_launch(void* const* d_in, const int* in_sizes, int n_in,
                              void* d_out, int out_size, void* d_ws, size_t ws_size,
                              hipStream_t stream) {
    const float* x      = (const float*)d_in[0];  // [N, 256]
    const float* W      = (const float*)d_in[1];  // [8, 256, 256]
    const float* attn_l = (const float*)d_in[2];  // [8, 16, 16]
    const float* attn_r = (const float*)d_in[3];  // [8, 16, 16]
    const int*   etype  = (const int*)d_in[4];    // [N]
    const int*   src    = (const int*)d_in[5];    // [E]
    const int*   dst    = (const int*)d_in[6];    // [E]

    int N = in_sizes[4];
    int E = in_sizes[5];

    float* out = (float*)d_out;  // [E, 16]

    // Workspace layout (16B alignment maintained; ~46 MB total).
    char* ws = (char*)d_ws;
    float4* Wc    = (float4*)ws;                          // 8*256*8 float4 = 256 KB
    float*  el    = (float*)(Wc + (size_t)NT * IN_F * 8); // N*16 floats
    float*  ernv  = el + (size_t)N * NH;                  // N*16 float2 (flat floats)
    int*    cnt   = (int*)(ernv + (size_t)N * NH * 2);    // N
    int*    startv= cnt + N;                              // N
    int*    pos   = startv + N;                           // E
    int*    srcs  = pos + E;                              // E

    hipMemsetAsync(cnt, 0, (size_t)N * sizeof(int), stream);

    precompute_w_kernel<<<NT, 256, 0, stream>>>(W, attn_l, attn_r, Wc);

    int nb_proj = (N + TM - 1) / TM;
    node_proj_kernel<<<nb_proj, 256, 0, stream>>>(x, etype, Wc, el, ernv, N);

    int nb_edge = (E + 255) / 256;
    count_pos_kernel<<<nb_edge, 256, 0, stream>>>(dst, cnt, pos, E);
    scan_kernel<<<1, 1024, 0, stream>>>(cnt, startv, N);
    scatter_kernel<<<nb_edge, 256, 0, stream>>>(dst, src, pos, startv, srcs, E);

    int nb_sum = (N + 3) / 4;
    node_sum_kernel<<<nb_sum, 256, 0, stream>>>(srcs, startv, cnt, el, ernv, N);

    size_t total_eh = (size_t)E * NH;
    int nb_fin = (int)((total_eh + 255) / 256);
    final_edge_kernel<<<nb_fin, 256, 0, stream>>>(src, dst, el, (const float2*)ernv, out, E);
}